// Round 2
// baseline (768.930 us; speedup 1.0000x reference)
//
#include <hip/hip_runtime.h>
#include <hip/hip_bf16.h>

#define B_N   16384
#define H_DIM 768
#define HH    384      // H/2
#define NE    8
#define TILE  64
#define NTHR  256
#define BK    64

// ws layout: counts[NE] ints, then buckets[NE][B_N] ints (~0.5 MB)

__global__ void zero_counts_kernel(int* __restrict__ counts) {
    if (threadIdx.x < NE) counts[threadIdx.x] = 0;
}

__global__ void route_kernel(const float* __restrict__ logits,
                             int* __restrict__ counts,
                             int* __restrict__ buckets) {
    int b = blockIdx.x * blockDim.x + threadIdx.x;
    if (b >= B_N) return;
    const float* l = logits + (size_t)b * NE;
    float best = l[0];
    int be = 0;
#pragma unroll
    for (int e = 1; e < NE; ++e) {
        float v = l[e];
        if (v > best) { best = v; be = e; }   // strict > keeps first index (jnp.argmax tie-break)
    }
    int pos = atomicAdd(&counts[be], 1);
    buckets[be * B_N + pos] = b;
}

// One block = 64 samples of one expert. 256 threads = 8 sample-groups x 32 col-lanes.
// Each thread: 8 samples x 12 columns register tile (outer-product FMAs).
// LDS: X chunk fp32 [64][64] (16KB) + H bf16 [64][384] (48KB) -> 2 blocks/CU.
__global__ __launch_bounds__(NTHR, 2)
void moe_fused_kernel(const float* __restrict__ emb,
                      const float* __restrict__ W1,
                      const float* __restrict__ b1,
                      const float* __restrict__ W2,
                      const float* __restrict__ b2,
                      const int* __restrict__ counts,
                      const int* __restrict__ buckets,
                      float* __restrict__ out) {
    __shared__ float Xs[TILE][BK];
    __shared__ __hip_bfloat16 Hs[TILE][HH];
    __shared__ int   sidx[TILE];
    __shared__ float s_in1[TILE];
    __shared__ float s_in2[TILE];

    const int e    = blockIdx.y;
    const int cnt  = counts[e];
    const int base = blockIdx.x * TILE;
    if (base >= cnt) return;
    const int ns = min(TILE, cnt - base);

    const int tid = threadIdx.x;
    const int sg  = tid >> 5;   // 0..7
    const int cg  = tid & 31;   // 0..31

    if (tid < TILE) {
        int p = base + ((tid < ns) ? tid : 0);   // clamp: duplicates are compute-only, stores guarded
        sidx[tid] = buckets[e * B_N + p];
    }
    __syncthreads();

    // -------- layer 1: H = relu(X @ W1[e] + b1[e]) --------
    float acc[8][12];
#pragma unroll
    for (int i = 0; i < 8; ++i)
#pragma unroll
        for (int j = 0; j < 12; ++j) acc[i][j] = 0.f;

    const float* W1e = W1 + (size_t)e * H_DIM * HH;
    const int r = tid >> 2;          // staging row 0..63
    const int q = tid & 3;           // staging quarter of a 64-float row
    const float* xrow = emb + (size_t)sidx[r] * H_DIM;

    for (int kk = 0; kk < H_DIM; kk += BK) {
#pragma unroll
        for (int i = 0; i < 4; ++i) {
            float4 v = *reinterpret_cast<const float4*>(xrow + kk + q * 16 + i * 4);
            *reinterpret_cast<float4*>(&Xs[r][q * 16 + i * 4]) = v;
        }
        __syncthreads();
#pragma unroll 2
        for (int k = 0; k < BK; ++k) {
            float xv[8], wv[12];
            const float* wrow = W1e + (size_t)(kk + k) * HH + cg;
#pragma unroll
            for (int j = 0; j < 12; ++j) wv[j] = wrow[j * 32];
#pragma unroll
            for (int i = 0; i < 8; ++i) xv[i] = Xs[sg * 8 + i][k];
#pragma unroll
            for (int i = 0; i < 8; ++i)
#pragma unroll
                for (int j = 0; j < 12; ++j)
                    acc[i][j] = fmaf(xv[i], wv[j], acc[i][j]);
        }
        __syncthreads();
    }

    const float* b1e = b1 + e * HH;
#pragma unroll
    for (int j = 0; j < 12; ++j) {
        float bb = b1e[cg + j * 32];
#pragma unroll
        for (int i = 0; i < 8; ++i) {
            float h = fmaxf(acc[i][j] + bb, 0.f);
            Hs[sg * 8 + i][cg + j * 32] = __float2bfloat16(h);
        }
    }
    __syncthreads();

    // -------- layer 2 + norm statistics, two N-halves of 384 --------
    const float* W2e = W2 + (size_t)e * HH * H_DIM;
    const float* b2e = b2 + e * H_DIM;
    float S1[8], S2[8], S3[8];   // ||y2||^2, y2.x, ||x||^2 partials per sample
#pragma unroll
    for (int i = 0; i < 8; ++i) { S1[i] = 0.f; S2[i] = 0.f; S3[i] = 0.f; }

    for (int hb = 0; hb < H_DIM; hb += 384) {
        float acc2[8][12];
#pragma unroll
        for (int i = 0; i < 8; ++i)
#pragma unroll
            for (int j = 0; j < 12; ++j) acc2[i][j] = 0.f;

#pragma unroll 2
        for (int k = 0; k < HH; ++k) {
            float hv[8], wv[12];
            const float* wrow = W2e + (size_t)k * H_DIM + hb + cg;
#pragma unroll
            for (int j = 0; j < 12; ++j) wv[j] = wrow[j * 32];
#pragma unroll
            for (int i = 0; i < 8; ++i) hv[i] = __bfloat162float(Hs[sg * 8 + i][k]);
#pragma unroll
            for (int i = 0; i < 8; ++i)
#pragma unroll
                for (int j = 0; j < 12; ++j)
                    acc2[i][j] = fmaf(hv[i], wv[j], acc2[i][j]);
        }

#pragma unroll
        for (int j = 0; j < 12; ++j) {
            int col = hb + cg + j * 32;
            float bb = b2e[col];
#pragma unroll
            for (int i = 0; i < 8; ++i) {
                int s = sg * 8 + i;
                float y = acc2[i][j] + bb;
                size_t o = (size_t)sidx[s] * H_DIM + col;
                float x = emb[o];
                S1[i] = fmaf(y, y, S1[i]);
                S2[i] = fmaf(y, x, S2[i]);
                S3[i] = fmaf(x, x, S3[i]);
                if (s < ns) out[o] = y;   // temp store of raw y2
            }
        }
    }

    // -------- per-sample norms: reduce across 32 cg lanes via shuffle --------
#pragma unroll
    for (int i = 0; i < 8; ++i) {
        float v1 = S1[i], v2 = S2[i], v3 = S3[i];
#pragma unroll
        for (int m = 1; m < 32; m <<= 1) {
            v1 += __shfl_xor(v1, m);
            v2 += __shfl_xor(v2, m);
            v3 += __shfl_xor(v3, m);
        }
        if (cg == 0) {
            float n1 = fmaxf(sqrtf(v1), 1e-6f);             // ||y2|| clamped (EPS_COMBINE)
            float t  = v1 / (n1 * n1) + 2.f * v2 / n1 + v3; // ||y2/n1 + x||^2
            float n2 = fmaxf(sqrtf(t), 1e-12f);             // EPS_FINAL
            s_in1[sg * 8 + i] = 1.f / n1;
            s_in2[sg * 8 + i] = 1.f / n2;
        }
    }
    __syncthreads();

    // -------- final pass: out = (y2/n1 + x)/n2 --------
#pragma unroll
    for (int i = 0; i < 8; ++i) {
        int s = sg * 8 + i;
        if (s >= ns) continue;
        float in1 = s_in1[s];
        float in2 = s_in2[s];
        size_t rowo = (size_t)sidx[s] * H_DIM;
#pragma unroll
        for (int j = 0; j < 24; ++j) {
            int col = cg + j * 32;
            float y = out[rowo + col];   // re-read own temp store (same thread, program order)
            float x = emb[rowo + col];
            out[rowo + col] = (y * in1 + x) * in2;
        }
    }
}

extern "C" void kernel_launch(void* const* d_in, const int* in_sizes, int n_in,
                              void* d_out, int out_size, void* d_ws, size_t ws_size,
                              hipStream_t stream) {
    const float* emb    = (const float*)d_in[0];
    const float* logits = (const float*)d_in[1];
    const float* W1     = (const float*)d_in[2];
    const float* b1     = (const float*)d_in[3];
    const float* W2     = (const float*)d_in[4];
    const float* b2     = (const float*)d_in[5];
    float* out = (float*)d_out;

    int* counts  = (int*)d_ws;
    int* buckets = counts + NE;

    zero_counts_kernel<<<1, 64, 0, stream>>>(counts);
    route_kernel<<<B_N / 256, 256, 0, stream>>>(logits, counts, buckets);

    dim3 grid(B_N / TILE, NE);
    moe_fused_kernel<<<grid, NTHR, 0, stream>>>(emb, W1, b1, W2, b2, counts, buckets, out);
}

// Round 4
// 274.975 us; speedup vs baseline: 2.7964x; 2.7964x over previous
//
#include <hip/hip_runtime.h>
#include <hip/hip_bf16.h>
#include <stdint.h>

#define B_N   16384
#define H_DIM 768
#define HH    384
#define NE    8

typedef __attribute__((ext_vector_type(8))) short bf16x8;
typedef __attribute__((ext_vector_type(4))) float f32x4;

__device__ __forceinline__ unsigned short f2bf(float f) {
    uint32_t u = __float_as_uint(f);
    return (unsigned short)((u + 0x7fffu + ((u >> 16) & 1u)) >> 16);   // RNE
}

// ---------------- routing ----------------
__global__ void zero_counts_kernel(int* __restrict__ counts) {
    if (threadIdx.x < NE) counts[threadIdx.x] = 0;
}

__global__ void route_kernel(const float* __restrict__ logits,
                             int* __restrict__ counts,
                             int* __restrict__ buckets) {
    int b = blockIdx.x * blockDim.x + threadIdx.x;
    if (b >= B_N) return;
    const float* l = logits + (size_t)b * NE;
    float best = l[0];
    int be = 0;
#pragma unroll
    for (int e = 1; e < NE; ++e) {
        float v = l[e];
        if (v > best) { best = v; be = e; }   // strict >: first-index tie-break (jnp.argmax)
    }
    int pos = atomicAdd(&counts[be], 1);
    buckets[be * B_N + pos] = b;
}

// ---------------- W transpose + bf16 cvt ----------------
// z=0: W1 [8][768][384] -> W1T bf16 [8][384][768]
// z=1: W2 [8][384][768] -> W2T bf16 [8][768][384]
__global__ void transpose_cvt_kernel(const float* __restrict__ W1,
                                     const float* __restrict__ W2,
                                     unsigned short* __restrict__ W1T,
                                     unsigned short* __restrict__ W2T) {
    const int z = blockIdx.z;
    const int R = z ? HH : H_DIM;     // src rows
    const int C = z ? H_DIM : HH;     // src cols
    const float* src = (z ? W2 : W1) + (size_t)blockIdx.y * R * C;
    unsigned short* dst = (z ? W2T : W1T) + (size_t)blockIdx.y * R * C;

    const int ctiles = C >> 5;
    const int ty = blockIdx.x / ctiles;
    const int tx = blockIdx.x % ctiles;

    __shared__ float Ts[32][33];
    const int lr = threadIdx.x >> 3;
    const int lc = (threadIdx.x & 7) * 4;

    f32x4 v = *reinterpret_cast<const f32x4*>(src + (size_t)(ty * 32 + lr) * C + tx * 32 + lc);
    Ts[lr][lc + 0] = v[0]; Ts[lr][lc + 1] = v[1];
    Ts[lr][lc + 2] = v[2]; Ts[lr][lc + 3] = v[3];
    __syncthreads();

    ushort4 o;
    o.x = f2bf(Ts[lc + 0][lr]);
    o.y = f2bf(Ts[lc + 1][lr]);
    o.z = f2bf(Ts[lc + 2][lr]);
    o.w = f2bf(Ts[lc + 3][lr]);
    *reinterpret_cast<ushort4*>(dst + (size_t)(tx * 32 + lr) * R + ty * 32 + lc) = o;
}

// ---------------- MFMA GEMM (shared template) ----------------
// C[m][n] = act( A[m][:] @ WT[n][:]^T + bias[n] )
// A rows gathered via buckets. Block tile 64(M) x 128(N), BK=64, 4 waves (2x2).
// LDS XOR-swizzle: byte kb ^ ((row&7)<<4); reg-staged both sides (rule #21).
template<int KTOT, int NTOT, bool A_F32, bool RELU_BF16>
__global__ __launch_bounds__(256, 4)
void gemm_kernel(const void* __restrict__ Aglob,
                 const unsigned short* __restrict__ WT,   // [NE][NTOT][KTOT] bf16
                 const float* __restrict__ bias,          // [NE][NTOT]
                 const int* __restrict__ counts,
                 const int* __restrict__ buckets,
                 void* __restrict__ Cout) {               // RELU_BF16 ? ushort H : float out
    __shared__ __align__(16) unsigned char AsB[64 * 128];   // 64 rows x 128B (64 bf16)
    __shared__ __align__(16) unsigned char BsB[128 * 128];  // 128 rows x 128B
    __shared__ int sidx[64];

    const int e      = blockIdx.y;
    const int cnt    = counts[e];
    const int mtile  = blockIdx.x & 255;
    const int nchunk = blockIdx.x >> 8;
    const int base   = mtile * 64;
    if (base >= cnt) return;
    const int ns  = min(64, cnt - base);
    const int tid = threadIdx.x;

    if (tid < 64) sidx[tid] = buckets[e * B_N + base + (tid < ns ? tid : 0)];
    __syncthreads();

    // staging roles
    const int ar = tid >> 2, aq = tid & 3;     // A: row 0..63, 16-elt quarter
    const int bn = tid >> 1, bh = tid & 1;     // B: row 0..127, 32-elt half
    const float*          arow_f = nullptr;
    const unsigned short* arow_h = nullptr;
    if (A_F32) arow_f = (const float*)Aglob + (size_t)sidx[ar] * KTOT;
    else       arow_h = (const unsigned short*)Aglob + (size_t)sidx[ar] * KTOT;
    const unsigned short* brow =
        WT + ((size_t)e * NTOT + nchunk * 128 + bn) * KTOT;

    // wave roles
    const int w = tid >> 6, lane = tid & 63;
    const int wr = w >> 1, wc = w & 1;
    const int fr = lane & 15, fq = lane >> 4;

    f32x4 acc[2][4];
#pragma unroll
    for (int mi = 0; mi < 2; ++mi)
#pragma unroll
        for (int ni = 0; ni < 4; ++ni) acc[mi][ni] = (f32x4)(0.f);

    for (int k0 = 0; k0 < KTOT; k0 += 64) {
        // ---- stage A (64 rows x 64 bf16): 4 threads/row x 16 elts ----
        if (A_F32) {
            const float* ap = arow_f + k0 + aq * 16;
            f32x4 f0 = *reinterpret_cast<const f32x4*>(ap + 0);
            f32x4 f1 = *reinterpret_cast<const f32x4*>(ap + 4);
            f32x4 f2 = *reinterpret_cast<const f32x4*>(ap + 8);
            f32x4 f3 = *reinterpret_cast<const f32x4*>(ap + 12);
            bf16x8 p0, p1;
#pragma unroll
            for (int i = 0; i < 4; ++i) {
                p0[i]     = (short)f2bf(f0[i]);
                p0[i + 4] = (short)f2bf(f1[i]);
                p1[i]     = (short)f2bf(f2[i]);
                p1[i + 4] = (short)f2bf(f3[i]);
            }
            const int kb0 = aq * 32, sw = (ar & 7) << 4;
            *reinterpret_cast<bf16x8*>(&AsB[(ar << 7) + ((kb0)      ^ sw)]) = p0;
            *reinterpret_cast<bf16x8*>(&AsB[(ar << 7) + ((kb0 + 16) ^ sw)]) = p1;
        } else {
            const unsigned short* ap = arow_h + k0 + aq * 16;
            f32x4 c0 = *reinterpret_cast<const f32x4*>(ap + 0);
            f32x4 c1 = *reinterpret_cast<const f32x4*>(ap + 8);
            const int kb0 = aq * 32, sw = (ar & 7) << 4;
            *reinterpret_cast<f32x4*>(&AsB[(ar << 7) + ((kb0)      ^ sw)]) = c0;
            *reinterpret_cast<f32x4*>(&AsB[(ar << 7) + ((kb0 + 16) ^ sw)]) = c1;
        }
        // ---- stage B (128 rows x 64 bf16): 2 threads/row x 32 elts (FIXED: full 64B/thread) ----
        {
            const unsigned short* bp = brow + k0 + bh * 32;
            f32x4 c0 = *reinterpret_cast<const f32x4*>(bp + 0);    // elts [ 0, 8)
            f32x4 c1 = *reinterpret_cast<const f32x4*>(bp + 8);    // elts [ 8,16)
            f32x4 c2 = *reinterpret_cast<const f32x4*>(bp + 16);   // elts [16,24)
            f32x4 c3 = *reinterpret_cast<const f32x4*>(bp + 24);   // elts [24,32)
            const int kb0 = bh * 64, sw = (bn & 7) << 4;
            *reinterpret_cast<f32x4*>(&BsB[(bn << 7) + ((kb0)      ^ sw)]) = c0;
            *reinterpret_cast<f32x4*>(&BsB[(bn << 7) + ((kb0 + 16) ^ sw)]) = c1;
            *reinterpret_cast<f32x4*>(&BsB[(bn << 7) + ((kb0 + 32) ^ sw)]) = c2;
            *reinterpret_cast<f32x4*>(&BsB[(bn << 7) + ((kb0 + 48) ^ sw)]) = c3;
        }
        __syncthreads();

#pragma unroll
        for (int s = 0; s < 2; ++s) {
            bf16x8 af[2], bf[4];
            const int kb = s * 64 + fq * 16;
#pragma unroll
            for (int mi = 0; mi < 2; ++mi) {
                int row = wr * 32 + mi * 16 + fr;
                af[mi] = *reinterpret_cast<const bf16x8*>(&AsB[(row << 7) + (kb ^ ((row & 7) << 4))]);
            }
#pragma unroll
            for (int ni = 0; ni < 4; ++ni) {
                int row = wc * 64 + ni * 16 + fr;
                bf[ni] = *reinterpret_cast<const bf16x8*>(&BsB[(row << 7) + (kb ^ ((row & 7) << 4))]);
            }
#pragma unroll
            for (int mi = 0; mi < 2; ++mi)
#pragma unroll
                for (int ni = 0; ni < 4; ++ni)
                    acc[mi][ni] = __builtin_amdgcn_mfma_f32_16x16x32_bf16(
                        af[mi], bf[ni], acc[mi][ni], 0, 0, 0);
        }
        __syncthreads();
    }

    // ---- epilogue ----
    const float* be = bias + (size_t)e * NTOT + nchunk * 128 + wc * 64;
#pragma unroll
    for (int mi = 0; mi < 2; ++mi) {
        const int rl0 = wr * 32 + mi * 16 + fq * 4;
        int  sid[4];
        bool val[4];
#pragma unroll
        for (int r2 = 0; r2 < 4; ++r2) {
            int rl = rl0 + r2;
            val[r2] = (rl < ns);
            sid[r2] = sidx[rl];
        }
#pragma unroll
        for (int ni = 0; ni < 4; ++ni) {
            const int coll = ni * 16 + fr;
            const int colg = nchunk * 128 + wc * 64 + coll;
            const float bb = be[coll];
#pragma unroll
            for (int r2 = 0; r2 < 4; ++r2) {
                float v = acc[mi][ni][r2] + bb;
                if (RELU_BF16) {
                    v = fmaxf(v, 0.f);
                    if (val[r2])
                        ((unsigned short*)Cout)[(size_t)sid[r2] * NTOT + colg] = f2bf(v);
                } else {
                    if (val[r2])
                        ((float*)Cout)[(size_t)sid[r2] * NTOT + colg] = v;
                }
            }
        }
    }
}

// ---------------- final norm: out = l2norm(l2norm(y2) + x) ----------------
__global__ void norm_kernel(const float* __restrict__ emb, float* __restrict__ out) {
    const int row  = blockIdx.x * 4 + (threadIdx.x >> 6);
    const int lane = threadIdx.x & 63;
    float* y = out + (size_t)row * H_DIM;
    const float* x = emb + (size_t)row * H_DIM;

    f32x4 yv[3], xv[3];
    float s1 = 0.f, s2 = 0.f, s3 = 0.f;
#pragma unroll
    for (int c = 0; c < 3; ++c) {
        int col = c * 256 + lane * 4;
        yv[c] = *reinterpret_cast<const f32x4*>(y + col);
        xv[c] = *reinterpret_cast<const f32x4*>(x + col);
#pragma unroll
        for (int i = 0; i < 4; ++i) {
            s1 = fmaf(yv[c][i], yv[c][i], s1);
            s2 = fmaf(yv[c][i], xv[c][i], s2);
            s3 = fmaf(xv[c][i], xv[c][i], s3);
        }
    }
#pragma unroll
    for (int m = 1; m < 64; m <<= 1) {
        s1 += __shfl_xor(s1, m);
        s2 += __shfl_xor(s2, m);
        s3 += __shfl_xor(s3, m);
    }
    const float n1 = fmaxf(sqrtf(s1), 1e-6f);
    const float i1 = 1.f / n1;
    const float t  = s1 * i1 * i1 + 2.f * s2 * i1 + s3;   // ||y2/n1 + x||^2
    const float i2 = 1.f / fmaxf(sqrtf(t), 1e-12f);
#pragma unroll
    for (int c = 0; c < 3; ++c) {
        int col = c * 256 + lane * 4;
        f32x4 o;
#pragma unroll
        for (int i = 0; i < 4; ++i) o[i] = (yv[c][i] * i1 + xv[c][i]) * i2;
        *reinterpret_cast<f32x4*>(y + col) = o;
    }
}

// ---------------- fallback (round-2 kernel) if ws too small ----------------
#define TILE 64
#define NTHR 256
#define BK   64
__global__ __launch_bounds__(NTHR, 2)
void moe_fused_fallback(const float* __restrict__ emb,
                        const float* __restrict__ W1,
                        const float* __restrict__ b1,
                        const float* __restrict__ W2,
                        const float* __restrict__ b2,
                        const int* __restrict__ counts,
                        const int* __restrict__ buckets,
                        float* __restrict__ out) {
    __shared__ float Xs[TILE][BK];
    __shared__ __hip_bfloat16 Hs[TILE][HH];
    __shared__ int   sidx[TILE];
    __shared__ float s_in1[TILE];
    __shared__ float s_in2[TILE];

    const int e    = blockIdx.y;
    const int cnt  = counts[e];
    const int base = blockIdx.x * TILE;
    if (base >= cnt) return;
    const int ns = min(TILE, cnt - base);
    const int tid = threadIdx.x;
    const int sg  = tid >> 5;
    const int cg  = tid & 31;

    if (tid < TILE) sidx[tid] = buckets[e * B_N + base + ((tid < ns) ? tid : 0)];
    __syncthreads();

    float acc[8][12];
#pragma unroll
    for (int i = 0; i < 8; ++i)
#pragma unroll
        for (int j = 0; j < 12; ++j) acc[i][j] = 0.f;

    const float* W1e = W1 + (size_t)e * H_DIM * HH;
    const int r = tid >> 2, q = tid & 3;
    const float* xrow = emb + (size_t)sidx[r] * H_DIM;

    for (int kk = 0; kk < H_DIM; kk += BK) {
#pragma unroll
        for (int i = 0; i < 4; ++i)
            *reinterpret_cast<float4*>(&Xs[r][q * 16 + i * 4]) =
                *reinterpret_cast<const float4*>(xrow + kk + q * 16 + i * 4);
        __syncthreads();
#pragma unroll 2
        for (int k = 0; k < BK; ++k) {
            float xv[8], wv[12];
            const float* wrow = W1e + (size_t)(kk + k) * HH + cg;
#pragma unroll
            for (int j = 0; j < 12; ++j) wv[j] = wrow[j * 32];
#pragma unroll
            for (int i = 0; i < 8; ++i) xv[i] = Xs[sg * 8 + i][k];
#pragma unroll
            for (int i = 0; i < 8; ++i)
#pragma unroll
                for (int j = 0; j < 12; ++j) acc[i][j] = fmaf(xv[i], wv[j], acc[i][j]);
        }
        __syncthreads();
    }
    const float* b1e = b1 + e * HH;
#pragma unroll
    for (int j = 0; j < 12; ++j) {
        float bb = b1e[cg + j * 32];
#pragma unroll
        for (int i = 0; i < 8; ++i)
            Hs[sg * 8 + i][cg + j * 32] = __float2bfloat16(fmaxf(acc[i][j] + bb, 0.f));
    }
    __syncthreads();

    const float* W2e = W2 + (size_t)e * HH * H_DIM;
    const float* b2e = b2 + e * H_DIM;
    float S1[8], S2[8], S3[8];
#pragma unroll
    for (int i = 0; i < 8; ++i) { S1[i] = 0.f; S2[i] = 0.f; S3[i] = 0.f; }

    for (int hb = 0; hb < H_DIM; hb += 384) {
        float acc2[8][12];
#pragma unroll
        for (int i = 0; i < 8; ++i)
#pragma unroll
            for (int j = 0; j < 12; ++j) acc2[i][j] = 0.f;
#pragma unroll 2
        for (int k = 0; k < HH; ++k) {
            float hv[8], wv[12];
            const float* wrow = W2e + (size_t)k * H_DIM + hb + cg;
#pragma unroll
            for (int j = 0; j < 12; ++j) wv[j] = wrow[j * 32];
#pragma unroll
            for (int i = 0; i < 8; ++i) hv[i] = __bfloat162float(Hs[sg * 8 + i][k]);
#pragma unroll
            for (int i = 0; i < 8; ++i)
#pragma unroll
                for (int j = 0; j < 12; ++j) acc2[i][j] = fmaf(hv[i], wv[j], acc2[i][j]);
        }
#pragma unroll
        for (int j = 0; j < 12; ++j) {
            int col = hb + cg + j * 32;
            float bb = b2e[col];
#pragma unroll
            for (int i = 0; i < 8; ++i) {
                int s = sg * 8 + i;
                float y = acc2[i][j] + bb;
                size_t o = (size_t)sidx[s] * H_DIM + col;
                float x = emb[o];
                S1[i] = fmaf(y, y, S1[i]);
                S2[i] = fmaf(y, x, S2[i]);
                S3[i] = fmaf(x, x, S3[i]);
                if (s < ns) out[o] = y;
            }
        }
    }
#pragma unroll
    for (int i = 0; i < 8; ++i) {
        float v1 = S1[i], v2 = S2[i], v3 = S3[i];
#pragma unroll
        for (int m = 1; m < 32; m <<= 1) {
            v1 += __shfl_xor(v1, m); v2 += __shfl_xor(v2, m); v3 += __shfl_xor(v3, m);
        }
        if (cg == 0) {
            float n1 = fmaxf(sqrtf(v1), 1e-6f);
            float t  = v1 / (n1 * n1) + 2.f * v2 / n1 + v3;
            s_in1[sg * 8 + i] = 1.f / n1;
            s_in2[sg * 8 + i] = 1.f / fmaxf(sqrtf(t), 1e-12f);
        }
    }
    __syncthreads();
#pragma unroll
    for (int i = 0; i < 8; ++i) {
        int s = sg * 8 + i;
        if (s >= ns) continue;
        float in1 = s_in1[s], in2 = s_in2[s];
        size_t rowo = (size_t)sidx[s] * H_DIM;
#pragma unroll
        for (int j = 0; j < 24; ++j) {
            int col = cg + j * 32;
            out[rowo + col] = (out[rowo + col] * in1 + emb[rowo + col]) * in2;
        }
    }
}

// ---------------- launch ----------------
extern "C" void kernel_launch(void* const* d_in, const int* in_sizes, int n_in,
                              void* d_out, int out_size, void* d_ws, size_t ws_size,
                              hipStream_t stream) {
    const float* emb    = (const float*)d_in[0];
    const float* logits = (const float*)d_in[1];
    const float* W1     = (const float*)d_in[2];
    const float* b1     = (const float*)d_in[3];
    const float* W2     = (const float*)d_in[4];
    const float* b2     = (const float*)d_in[5];
    float* out = (float*)d_out;

    int* counts  = (int*)d_ws;
    int* buckets = (int*)((char*)d_ws + 256);
    unsigned short* W1T = (unsigned short*)((char*)d_ws + 524544);
    unsigned short* W2T = W1T + (size_t)NE * HH * H_DIM;   // 2359296 elts
    unsigned short* Hws = W2T + (size_t)NE * HH * H_DIM;
    const size_t needed = 524544
                        + 2 * (size_t)NE * HH * H_DIM * sizeof(unsigned short)
                        + (size_t)B_N * HH * sizeof(unsigned short);

    zero_counts_kernel<<<1, 64, 0, stream>>>(counts);
    route_kernel<<<B_N / 256, 256, 0, stream>>>(logits, counts, buckets);

    if (ws_size >= needed) {
        transpose_cvt_kernel<<<dim3(288, NE, 2), 256, 0, stream>>>(W1, W2, W1T, W2T);
        gemm_kernel<H_DIM, HH, true, true>
            <<<dim3(256 * 3, NE), 256, 0, stream>>>(emb, W1T, b1, counts, buckets, Hws);
        gemm_kernel<HH, H_DIM, false, false>
            <<<dim3(256 * 6, NE), 256, 0, stream>>>(Hws, W2T, b2, counts, buckets, out);
        norm_kernel<<<B_N / 4, 256, 0, stream>>>(emb, out);
    } else {
        moe_fused_fallback<<<dim3(B_N / TILE, NE), NTHR, 0, stream>>>(
            emb, W1, b1, W2, b2, counts, buckets, out);
    }
}

// Round 7
// 214.783 us; speedup vs baseline: 3.5800x; 1.2802x over previous
//
#include <hip/hip_runtime.h>
#include <hip/hip_bf16.h>
#include <stdint.h>

#define B_N   16384
#define H_DIM 768
#define HH    384
#define NE    8
#define CSTRIDE 32   // counts padded: one counter per 128B line

typedef __attribute__((ext_vector_type(8))) short bf16x8;
typedef __attribute__((ext_vector_type(4))) float f32x4;

__device__ __forceinline__ unsigned short f2bf(float f) {
    uint32_t u = __float_as_uint(f);
    return (unsigned short)((u + 0x7fffu + ((u >> 16) & 1u)) >> 16);   // RNE
}

// ---------------- routing (two-level: LDS histogram -> padded global counters) ----------------
__global__ void zero_counts_kernel(int* __restrict__ counts) {
    if (threadIdx.x < NE) counts[threadIdx.x * CSTRIDE] = 0;
}

__global__ void route_kernel(const float* __restrict__ logits,
                             int* __restrict__ counts,
                             int* __restrict__ buckets) {
    __shared__ int lcnt[NE];
    __shared__ int lbase[NE];
    const int tid = threadIdx.x;
    if (tid < NE) lcnt[tid] = 0;
    __syncthreads();

    const int b = blockIdx.x * 256 + tid;
    const float* l = logits + (size_t)b * NE;
    float best = l[0];
    int be = 0;
#pragma unroll
    for (int e = 1; e < NE; ++e) {
        float v = l[e];
        if (v > best) { best = v; be = e; }   // strict >: first-index tie-break (jnp.argmax)
    }
    const int lpos = atomicAdd(&lcnt[be], 1);
    __syncthreads();
    if (tid < NE) lbase[tid] = atomicAdd(&counts[tid * CSTRIDE], lcnt[tid]);
    __syncthreads();
    buckets[be * B_N + lbase[be] + lpos] = b;
}

// ---------------- W transpose + bf16 cvt (also zeroes padded counters) ----------------
// z=0: W1 [8][768][384] -> W1T bf16 [8][384][768]
// z=1: W2 [8][384][768] -> W2T bf16 [8][768][384]
__global__ void transpose_cvt_kernel(const float* __restrict__ W1,
                                     const float* __restrict__ W2,
                                     unsigned short* __restrict__ W1T,
                                     unsigned short* __restrict__ W2T,
                                     int* __restrict__ counts) {
    if (blockIdx.x == 0 && blockIdx.y == 0 && blockIdx.z == 0 && threadIdx.x < NE)
        counts[threadIdx.x * CSTRIDE] = 0;

    const int z = blockIdx.z;
    const int R = z ? HH : H_DIM;     // src rows
    const int C = z ? H_DIM : HH;     // src cols
    const float* src = (z ? W2 : W1) + (size_t)blockIdx.y * R * C;
    unsigned short* dst = (z ? W2T : W1T) + (size_t)blockIdx.y * R * C;

    const int ctiles = C >> 5;
    const int ty = blockIdx.x / ctiles;
    const int tx = blockIdx.x % ctiles;

    __shared__ float Ts[32][33];
    const int lr = threadIdx.x >> 3;
    const int lc = (threadIdx.x & 7) * 4;

    f32x4 v = *reinterpret_cast<const f32x4*>(src + (size_t)(ty * 32 + lr) * C + tx * 32 + lc);
    Ts[lr][lc + 0] = v[0]; Ts[lr][lc + 1] = v[1];
    Ts[lr][lc + 2] = v[2]; Ts[lr][lc + 3] = v[3];
    __syncthreads();

    ushort4 o;
    o.x = f2bf(Ts[lc + 0][lr]);
    o.y = f2bf(Ts[lc + 1][lr]);
    o.z = f2bf(Ts[lc + 2][lr]);
    o.w = f2bf(Ts[lc + 3][lr]);
    *reinterpret_cast<ushort4*>(dst + (size_t)(tx * 32 + lr) * R + ty * 32 + lc) = o;
}

// ---------------- MFMA GEMM (shared template) ----------------
// C[m][n] = act( A[m][:] @ WT[n][:]^T + bias[n] )
// A rows gathered via buckets. Block tile 64(M) x 128(N), BK=64, 4 waves (2x2).
// LDS XOR-swizzle: byte kb ^ ((row&7)<<4); reg-staged both sides (rule #21).
template<int KTOT, int NTOT, bool A_F32, bool RELU_BF16>
__global__ __launch_bounds__(256, 4)
void gemm_kernel(const void* __restrict__ Aglob,
                 const unsigned short* __restrict__ WT,   // [NE][NTOT][KTOT] bf16
                 const float* __restrict__ bias,          // [NE][NTOT]
                 const int* __restrict__ counts,
                 const int* __restrict__ buckets,
                 void* __restrict__ Cout) {               // RELU_BF16 ? ushort H : float out
    __shared__ __align__(16) unsigned char AsB[64 * 128];   // 64 rows x 128B (64 bf16)
    __shared__ __align__(16) unsigned char BsB[128 * 128];  // 128 rows x 128B
    __shared__ int sidx[64];

    const int e      = blockIdx.y;
    const int cnt    = counts[e * CSTRIDE];
    const int mtile  = blockIdx.x & 255;
    const int nchunk = blockIdx.x >> 8;
    const int base   = mtile * 64;
    if (base >= cnt) return;
    const int ns  = min(64, cnt - base);
    const int tid = threadIdx.x;

    if (tid < 64) sidx[tid] = buckets[e * B_N + base + (tid < ns ? tid : 0)];
    __syncthreads();

    // staging roles
    const int ar = tid >> 2, aq = tid & 3;     // A: row 0..63, 16-elt quarter
    const int bn = tid >> 1, bh = tid & 1;     // B: row 0..127, 32-elt half
    const float*          arow_f = nullptr;
    const unsigned short* arow_h = nullptr;
    if (A_F32) arow_f = (const float*)Aglob + (size_t)sidx[ar] * KTOT;
    else       arow_h = (const unsigned short*)Aglob + (size_t)sidx[ar] * KTOT;
    const unsigned short* brow =
        WT + ((size_t)e * NTOT + nchunk * 128 + bn) * KTOT;

    // wave roles
    const int w = tid >> 6, lane = tid & 63;
    const int wr = w >> 1, wc = w & 1;
    const int fr = lane & 15, fq = lane >> 4;

    f32x4 acc[2][4];
#pragma unroll
    for (int mi = 0; mi < 2; ++mi)
#pragma unroll
        for (int ni = 0; ni < 4; ++ni) acc[mi][ni] = (f32x4)(0.f);

    for (int k0 = 0; k0 < KTOT; k0 += 64) {
        // ---- stage A (64 rows x 64 bf16): 4 threads/row x 16 elts ----
        if (A_F32) {
            const float* ap = arow_f + k0 + aq * 16;
            f32x4 f0 = *reinterpret_cast<const f32x4*>(ap + 0);
            f32x4 f1 = *reinterpret_cast<const f32x4*>(ap + 4);
            f32x4 f2 = *reinterpret_cast<const f32x4*>(ap + 8);
            f32x4 f3 = *reinterpret_cast<const f32x4*>(ap + 12);
            bf16x8 p0, p1;
#pragma unroll
            for (int i = 0; i < 4; ++i) {
                p0[i]     = (short)f2bf(f0[i]);
                p0[i + 4] = (short)f2bf(f1[i]);
                p1[i]     = (short)f2bf(f2[i]);
                p1[i + 4] = (short)f2bf(f3[i]);
            }
            const int kb0 = aq * 32, sw = (ar & 7) << 4;
            *reinterpret_cast<bf16x8*>(&AsB[(ar << 7) + ((kb0)      ^ sw)]) = p0;
            *reinterpret_cast<bf16x8*>(&AsB[(ar << 7) + ((kb0 + 16) ^ sw)]) = p1;
        } else {
            const unsigned short* ap = arow_h + k0 + aq * 16;
            f32x4 c0 = *reinterpret_cast<const f32x4*>(ap + 0);
            f32x4 c1 = *reinterpret_cast<const f32x4*>(ap + 8);
            const int kb0 = aq * 32, sw = (ar & 7) << 4;
            *reinterpret_cast<f32x4*>(&AsB[(ar << 7) + ((kb0)      ^ sw)]) = c0;
            *reinterpret_cast<f32x4*>(&AsB[(ar << 7) + ((kb0 + 16) ^ sw)]) = c1;
        }
        // ---- stage B (128 rows x 64 bf16): 2 threads/row x 32 elts ----
        {
            const unsigned short* bp = brow + k0 + bh * 32;
            f32x4 c0 = *reinterpret_cast<const f32x4*>(bp + 0);    // elts [ 0, 8)
            f32x4 c1 = *reinterpret_cast<const f32x4*>(bp + 8);    // elts [ 8,16)
            f32x4 c2 = *reinterpret_cast<const f32x4*>(bp + 16);   // elts [16,24)
            f32x4 c3 = *reinterpret_cast<const f32x4*>(bp + 24);   // elts [24,32)
            const int kb0 = bh * 64, sw = (bn & 7) << 4;
            *reinterpret_cast<f32x4*>(&BsB[(bn << 7) + ((kb0)      ^ sw)]) = c0;
            *reinterpret_cast<f32x4*>(&BsB[(bn << 7) + ((kb0 + 16) ^ sw)]) = c1;
            *reinterpret_cast<f32x4*>(&BsB[(bn << 7) + ((kb0 + 32) ^ sw)]) = c2;
            *reinterpret_cast<f32x4*>(&BsB[(bn << 7) + ((kb0 + 48) ^ sw)]) = c3;
        }
        __syncthreads();

#pragma unroll
        for (int s = 0; s < 2; ++s) {
            bf16x8 af[2], bf[4];
            const int kb = s * 64 + fq * 16;
#pragma unroll
            for (int mi = 0; mi < 2; ++mi) {
                int row = wr * 32 + mi * 16 + fr;
                af[mi] = *reinterpret_cast<const bf16x8*>(&AsB[(row << 7) + (kb ^ ((row & 7) << 4))]);
            }
#pragma unroll
            for (int ni = 0; ni < 4; ++ni) {
                int row = wc * 64 + ni * 16 + fr;
                bf[ni] = *reinterpret_cast<const bf16x8*>(&BsB[(row << 7) + (kb ^ ((row & 7) << 4))]);
            }
#pragma unroll
            for (int mi = 0; mi < 2; ++mi)
#pragma unroll
                for (int ni = 0; ni < 4; ++ni)
                    acc[mi][ni] = __builtin_amdgcn_mfma_f32_16x16x32_bf16(
                        af[mi], bf[ni], acc[mi][ni], 0, 0, 0);
        }
        __syncthreads();
    }

    // ---- epilogue ----
    const float* be = bias + (size_t)e * NTOT + nchunk * 128 + wc * 64;
#pragma unroll
    for (int mi = 0; mi < 2; ++mi) {
        const int rl0 = wr * 32 + mi * 16 + fq * 4;
        int  sid[4];
        bool val[4];
#pragma unroll
        for (int r2 = 0; r2 < 4; ++r2) {
            int rl = rl0 + r2;
            val[r2] = (rl < ns);
            sid[r2] = sidx[rl];
        }
#pragma unroll
        for (int ni = 0; ni < 4; ++ni) {
            const int coll = ni * 16 + fr;
            const int colg = nchunk * 128 + wc * 64 + coll;
            const float bb = be[coll];
#pragma unroll
            for (int r2 = 0; r2 < 4; ++r2) {
                float v = acc[mi][ni][r2] + bb;
                if (RELU_BF16) {
                    v = fmaxf(v, 0.f);
                    if (val[r2])
                        ((unsigned short*)Cout)[(size_t)sid[r2] * NTOT + colg] = f2bf(v);
                } else {
                    if (val[r2])
                        ((float*)Cout)[(size_t)sid[r2] * NTOT + colg] = v;
                }
            }
        }
    }
}

// ---------------- final norm: out = l2norm(l2norm(y2) + x) ----------------
__global__ void norm_kernel(const float* __restrict__ emb, float* __restrict__ out) {
    const int row  = blockIdx.x * 4 + (threadIdx.x >> 6);
    const int lane = threadIdx.x & 63;
    float* y = out + (size_t)row * H_DIM;
    const float* x = emb + (size_t)row * H_DIM;

    f32x4 yv[3], xv[3];
    float s1 = 0.f, s2 = 0.f, s3 = 0.f;
#pragma unroll
    for (int c = 0; c < 3; ++c) {
        int col = c * 256 + lane * 4;
        yv[c] = *reinterpret_cast<const f32x4*>(y + col);
        xv[c] = *reinterpret_cast<const f32x4*>(x + col);
#pragma unroll
        for (int i = 0; i < 4; ++i) {
            s1 = fmaf(yv[c][i], yv[c][i], s1);
            s2 = fmaf(yv[c][i], xv[c][i], s2);
            s3 = fmaf(xv[c][i], xv[c][i], s3);
        }
    }
#pragma unroll
    for (int m = 1; m < 64; m <<= 1) {
        s1 += __shfl_xor(s1, m);
        s2 += __shfl_xor(s2, m);
        s3 += __shfl_xor(s3, m);
    }
    const float n1 = fmaxf(sqrtf(s1), 1e-6f);
    const float i1 = 1.f / n1;
    const float t  = s1 * i1 * i1 + 2.f * s2 * i1 + s3;   // ||y2/n1 + x||^2
    const float i2 = 1.f / fmaxf(sqrtf(t), 1e-12f);
#pragma unroll
    for (int c = 0; c < 3; ++c) {
        int col = c * 256 + lane * 4;
        f32x4 o;
#pragma unroll
        for (int i = 0; i < 4; ++i) o[i] = (yv[c][i] * i1 + xv[c][i]) * i2;
        *reinterpret_cast<f32x4*>(y + col) = o;
    }
}

// ---------------- fallback (fp32 fused) if ws too small ----------------
#define TILE 64
#define NTHR 256
#define BK   64
__global__ __launch_bounds__(NTHR, 2)
void moe_fused_fallback(const float* __restrict__ emb,
                        const float* __restrict__ W1,
                        const float* __restrict__ b1,
                        const float* __restrict__ W2,
                        const float* __restrict__ b2,
                        const int* __restrict__ counts,
                        const int* __restrict__ buckets,
                        float* __restrict__ out) {
    __shared__ float Xs[TILE][BK];
    __shared__ __hip_bfloat16 Hs[TILE][HH];
    __shared__ int   sidx[TILE];
    __shared__ float s_in1[TILE];
    __shared__ float s_in2[TILE];

    const int e    = blockIdx.y;
    const int cnt  = counts[e * CSTRIDE];
    const int base = blockIdx.x * TILE;
    if (base >= cnt) return;
    const int ns = min(TILE, cnt - base);
    const int tid = threadIdx.x;
    const int sg  = tid >> 5;
    const int cg  = tid & 31;

    if (tid < TILE) sidx[tid] = buckets[e * B_N + base + ((tid < ns) ? tid : 0)];
    __syncthreads();

    float acc[8][12];
#pragma unroll
    for (int i = 0; i < 8; ++i)
#pragma unroll
        for (int j = 0; j < 12; ++j) acc[i][j] = 0.f;

    const float* W1e = W1 + (size_t)e * H_DIM * HH;
    const int r = tid >> 2, q = tid & 3;
    const float* xrow = emb + (size_t)sidx[r] * H_DIM;

    for (int kk = 0; kk < H_DIM; kk += BK) {
#pragma unroll
        for (int i = 0; i < 4; ++i)
            *reinterpret_cast<float4*>(&Xs[r][q * 16 + i * 4]) =
                *reinterpret_cast<const float4*>(xrow + kk + q * 16 + i * 4);
        __syncthreads();
#pragma unroll 2
        for (int k = 0; k < BK; ++k) {
            float xv[8], wv[12];
            const float* wrow = W1e + (size_t)(kk + k) * HH + cg;
#pragma unroll
            for (int j = 0; j < 12; ++j) wv[j] = wrow[j * 32];
#pragma unroll
            for (int i = 0; i < 8; ++i) xv[i] = Xs[sg * 8 + i][k];
#pragma unroll
            for (int i = 0; i < 8; ++i)
#pragma unroll
                for (int j = 0; j < 12; ++j) acc[i][j] = fmaf(xv[i], wv[j], acc[i][j]);
        }
        __syncthreads();
    }
    const float* b1e = b1 + e * HH;
#pragma unroll
    for (int j = 0; j < 12; ++j) {
        float bb = b1e[cg + j * 32];
#pragma unroll
        for (int i = 0; i < 8; ++i)
            Hs[sg * 8 + i][cg + j * 32] = __float2bfloat16(fmaxf(acc[i][j] + bb, 0.f));
    }
    __syncthreads();

    const float* W2e = W2 + (size_t)e * HH * H_DIM;
    const float* b2e = b2 + e * H_DIM;
    float S1[8], S2[8], S3[8];
#pragma unroll
    for (int i = 0; i < 8; ++i) { S1[i] = 0.f; S2[i] = 0.f; S3[i] = 0.f; }

    for (int hb = 0; hb < H_DIM; hb += 384) {
        float acc2[8][12];
#pragma unroll
        for (int i = 0; i < 8; ++i)
#pragma unroll
            for (int j = 0; j < 12; ++j) acc2[i][j] = 0.f;
#pragma unroll 2
        for (int k = 0; k < HH; ++k) {
            float hv[8], wv[12];
            const float* wrow = W2e + (size_t)k * H_DIM + hb + cg;
#pragma unroll
            for (int j = 0; j < 12; ++j) wv[j] = wrow[j * 32];
#pragma unroll
            for (int i = 0; i < 8; ++i) hv[i] = __bfloat162float(Hs[sg * 8 + i][k]);
#pragma unroll
            for (int i = 0; i < 8; ++i)
#pragma unroll
                for (int j = 0; j < 12; ++j) acc2[i][j] = fmaf(hv[i], wv[j], acc2[i][j]);
        }
#pragma unroll
        for (int j = 0; j < 12; ++j) {
            int col = hb + cg + j * 32;
            float bb = b2e[col];
#pragma unroll
            for (int i = 0; i < 8; ++i) {
                int s = sg * 8 + i;
                float y = acc2[i][j] + bb;
                size_t o = (size_t)sidx[s] * H_DIM + col;
                float x = emb[o];
                S1[i] = fmaf(y, y, S1[i]);
                S2[i] = fmaf(y, x, S2[i]);
                S3[i] = fmaf(x, x, S3[i]);
                if (s < ns) out[o] = y;
            }
        }
    }
#pragma unroll
    for (int i = 0; i < 8; ++i) {
        float v1 = S1[i], v2 = S2[i], v3 = S3[i];
#pragma unroll
        for (int m = 1; m < 32; m <<= 1) {
            v1 += __shfl_xor(v1, m); v2 += __shfl_xor(v2, m); v3 += __shfl_xor(v3, m);
        }
        if (cg == 0) {
            float n1 = fmaxf(sqrtf(v1), 1e-6f);
            float t  = v1 / (n1 * n1) + 2.f * v2 / n1 + v3;
            s_in1[sg * 8 + i] = 1.f / n1;
            s_in2[sg * 8 + i] = 1.f / fmaxf(sqrtf(t), 1e-12f);
        }
    }
    __syncthreads();
#pragma unroll
    for (int i = 0; i < 8; ++i) {
        int s = sg * 8 + i;
        if (s >= ns) continue;
        float in1 = s_in1[s], in2 = s_in2[s];
        size_t rowo = (size_t)sidx[s] * H_DIM;
#pragma unroll
        for (int j = 0; j < 24; ++j) {
            int col = cg + j * 32;
            out[rowo + col] = (out[rowo + col] * in1 + emb[rowo + col]) * in2;
        }
    }
}

// ---------------- launch ----------------
extern "C" void kernel_launch(void* const* d_in, const int* in_sizes, int n_in,
                              void* d_out, int out_size, void* d_ws, size_t ws_size,
                              hipStream_t stream) {
    const float* emb    = (const float*)d_in[0];
    const float* logits = (const float*)d_in[1];
    const float* W1     = (const float*)d_in[2];
    const float* b1     = (const float*)d_in[3];
    const float* W2     = (const float*)d_in[4];
    const float* b2     = (const float*)d_in[5];
    float* out = (float*)d_out;

    int* counts  = (int*)d_ws;                              // 8 counters, 128B apart (1KB)
    int* buckets = (int*)((char*)d_ws + 1024);              // [8][16384] int
    unsigned short* W1T = (unsigned short*)((char*)d_ws + 1024 + 524288);
    unsigned short* W2T = W1T + (size_t)NE * HH * H_DIM;
    unsigned short* Hws = W2T + (size_t)NE * HH * H_DIM;
    const size_t needed = 1024 + 524288
                        + 2 * (size_t)NE * HH * H_DIM * sizeof(unsigned short)
                        + (size_t)B_N * HH * sizeof(unsigned short);

    if (ws_size >= needed) {
        transpose_cvt_kernel<<<dim3(288, NE, 2), 256, 0, stream>>>(W1, W2, W1T, W2T, counts);
        route_kernel<<<B_N / 256, 256, 0, stream>>>(logits, counts, buckets);
        gemm_kernel<H_DIM, HH, true, true>
            <<<dim3(256 * 3, NE), 256, 0, stream>>>(emb, W1T, b1, counts, buckets, Hws);
        gemm_kernel<HH, H_DIM, false, false>
            <<<dim3(256 * 6, NE), 256, 0, stream>>>(Hws, W2T, b2, counts, buckets, out);
        norm_kernel<<<B_N / 4, 256, 0, stream>>>(emb, out);
    } else {
        zero_counts_kernel<<<1, 64, 0, stream>>>(counts);
        route_kernel<<<B_N / 256, 256, 0, stream>>>(logits, counts, buckets);
        moe_fused_fallback<<<dim3(B_N / TILE, NE), NTHR, 0, stream>>>(
            emb, W1, b1, W2, b2, counts, buckets, out);
    }
}

// Round 9
// 186.163 us; speedup vs baseline: 4.1304x; 1.1537x over previous
//
#include <hip/hip_runtime.h>
#include <hip/hip_bf16.h>
#include <stdint.h>

#define B_N   16384
#define H_DIM 768
#define HH    384
#define NE    8
#define CSTRIDE 32   // counts padded: one counter per 128B line

typedef __attribute__((ext_vector_type(8))) short bf16x8;
typedef __attribute__((ext_vector_type(4))) float f32x4;

__device__ __forceinline__ unsigned short f2bf(float f) {
    uint32_t u = __float_as_uint(f);
    return (unsigned short)((u + 0x7fffu + ((u >> 16) & 1u)) >> 16);   // RNE
}

// ---------------- routing (two-level: LDS histogram -> padded global counters) ----------------
__global__ void zero_counts_kernel(int* __restrict__ counts) {
    if (threadIdx.x < NE) counts[threadIdx.x * CSTRIDE] = 0;
}

__global__ void route_kernel(const float* __restrict__ logits,
                             int* __restrict__ counts,
                             int* __restrict__ buckets) {
    __shared__ int lcnt[NE];
    __shared__ int lbase[NE];
    const int tid = threadIdx.x;
    if (tid < NE) lcnt[tid] = 0;
    __syncthreads();

    const int b = blockIdx.x * 256 + tid;
    const float* l = logits + (size_t)b * NE;
    float best = l[0];
    int be = 0;
#pragma unroll
    for (int e = 1; e < NE; ++e) {
        float v = l[e];
        if (v > best) { best = v; be = e; }   // strict >: first-index tie-break (jnp.argmax)
    }
    const int lpos = atomicAdd(&lcnt[be], 1);
    __syncthreads();
    if (tid < NE) lbase[tid] = atomicAdd(&counts[tid * CSTRIDE], lcnt[tid]);
    __syncthreads();
    buckets[be * B_N + lbase[be] + lpos] = b;
}

// ---------------- W transpose + bf16 cvt (also zeroes padded counters) ----------------
__global__ void transpose_cvt_kernel(const float* __restrict__ W1,
                                     const float* __restrict__ W2,
                                     unsigned short* __restrict__ W1T,
                                     unsigned short* __restrict__ W2T,
                                     int* __restrict__ counts) {
    if (blockIdx.x == 0 && blockIdx.y == 0 && blockIdx.z == 0 && threadIdx.x < NE)
        counts[threadIdx.x * CSTRIDE] = 0;

    const int z = blockIdx.z;
    const int R = z ? HH : H_DIM;
    const int C = z ? H_DIM : HH;
    const float* src = (z ? W2 : W1) + (size_t)blockIdx.y * R * C;
    unsigned short* dst = (z ? W2T : W1T) + (size_t)blockIdx.y * R * C;

    const int ctiles = C >> 5;
    const int ty = blockIdx.x / ctiles;
    const int tx = blockIdx.x % ctiles;

    __shared__ float Ts[32][33];
    const int lr = threadIdx.x >> 3;
    const int lc = (threadIdx.x & 7) * 4;

    f32x4 v = *reinterpret_cast<const f32x4*>(src + (size_t)(ty * 32 + lr) * C + tx * 32 + lc);
    Ts[lr][lc + 0] = v[0]; Ts[lr][lc + 1] = v[1];
    Ts[lr][lc + 2] = v[2]; Ts[lr][lc + 3] = v[3];
    __syncthreads();

    ushort4 o;
    o.x = f2bf(Ts[lc + 0][lr]);
    o.y = f2bf(Ts[lc + 1][lr]);
    o.z = f2bf(Ts[lc + 2][lr]);
    o.w = f2bf(Ts[lc + 3][lr]);
    *reinterpret_cast<ushort4*>(dst + (size_t)(tx * 32 + lr) * R + ty * 32 + lc) = o;
}

// ---------------- MFMA GEMM, 8 waves, double-buffered LDS, T14 pipeline ----------------
// Tile 64(M) x 128(N), BK=64. 512 thr. Wave (wr,wc) owns 32x32. 1D grid, e = wgid&7 (XCD affinity).
// LDS XOR-swizzle: byte k ^ ((row&7)<<4); reg-staged both sides.
template<int KTOT, int NTOT, bool A_F32, bool RELU, bool OUTBF>
__global__ __launch_bounds__(512, 6)
void gemm_kernel(const void* __restrict__ Aglob,
                 const unsigned short* __restrict__ WT,   // [NE][NTOT][KTOT] bf16
                 const float* __restrict__ bias,          // [NE][NTOT]
                 const int* __restrict__ counts,
                 const int* __restrict__ buckets,
                 void* __restrict__ Cout) {
    __shared__ __align__(16) unsigned char AsB[2][64 * 128];
    __shared__ __align__(16) unsigned char BsB[2][128 * 128];
    __shared__ int sidx[64];

    const int wgid   = blockIdx.x;
    const int e      = wgid & 7;          // XCD-affine expert
    const int rest   = wgid >> 3;
    const int mtile  = rest & 255;
    const int nchunk = rest >> 8;
    const int cnt    = counts[e * CSTRIDE];
    const int base   = mtile * 64;
    if (base >= cnt) return;
    const int ns  = min(64, cnt - base);
    const int tid = threadIdx.x;

    if (tid < 64) sidx[tid] = buckets[e * B_N + base + (tid < ns ? tid : 0)];
    __syncthreads();

    // staging roles: A 8 thr/row x 8 elts; B 4 thr/row x 16 elts
    const int ar = tid >> 3, aq = tid & 7;
    const int bn = tid >> 2, bq = tid & 3;
    const float*          arow_f = nullptr;
    const unsigned short* arow_h = nullptr;
    if (A_F32) arow_f = (const float*)Aglob + (size_t)sidx[ar] * KTOT + aq * 8;
    else       arow_h = (const unsigned short*)Aglob + (size_t)sidx[ar] * KTOT + aq * 8;
    const unsigned short* brow =
        WT + ((size_t)e * NTOT + nchunk * 128 + bn) * KTOT + bq * 16;

    const int a_slot  = (ar << 7) + ((aq * 16) ^ ((ar & 7) << 4));
    const int b_slot0 = (bn << 7) + (((bq * 32)     ) ^ ((bn & 7) << 4));
    const int b_slot1 = (bn << 7) + (((bq * 32) + 16) ^ ((bn & 7) << 4));

    // wave roles
    const int w = tid >> 6, lane = tid & 63;
    const int wr = w >> 2, wc = w & 3;
    const int fr = lane & 15, fq = lane >> 4;

    f32x4 acc[2][2];
#pragma unroll
    for (int mi = 0; mi < 2; ++mi)
#pragma unroll
        for (int ni = 0; ni < 2; ++ni) acc[mi][ni] = (f32x4)(0.f);

    bf16x8 aReg;
    f32x4  bReg0, bReg1;

    auto LOAD = [&](int k0) {
        if (A_F32) {
            f32x4 f0 = *reinterpret_cast<const f32x4*>(arow_f + k0);
            f32x4 f1 = *reinterpret_cast<const f32x4*>(arow_f + k0 + 4);
            bf16x8 p;
#pragma unroll
            for (int i = 0; i < 4; ++i) {
                p[i]     = (short)f2bf(f0[i]);
                p[i + 4] = (short)f2bf(f1[i]);
            }
            aReg = p;
        } else {
            aReg = *reinterpret_cast<const bf16x8*>(arow_h + k0);
        }
        bReg0 = *reinterpret_cast<const f32x4*>(brow + k0);
        bReg1 = *reinterpret_cast<const f32x4*>(brow + k0 + 8);
    };
    auto WRITE = [&](int buf) {
        *reinterpret_cast<bf16x8*>(&AsB[buf][a_slot])  = aReg;
        *reinterpret_cast<f32x4*>(&BsB[buf][b_slot0]) = bReg0;
        *reinterpret_cast<f32x4*>(&BsB[buf][b_slot1]) = bReg1;
    };
    auto COMPUTE = [&](int buf) {
#pragma unroll
        for (int s = 0; s < 2; ++s) {
            const int kb = s * 64 + fq * 16;
            bf16x8 af[2], bfr[2];
#pragma unroll
            for (int mi = 0; mi < 2; ++mi) {
                int row = wr * 32 + mi * 16 + fr;
                af[mi] = *reinterpret_cast<const bf16x8*>(
                    &AsB[buf][(row << 7) + (kb ^ ((row & 7) << 4))]);
            }
#pragma unroll
            for (int ni = 0; ni < 2; ++ni) {
                int row = wc * 32 + ni * 16 + fr;
                bfr[ni] = *reinterpret_cast<const bf16x8*>(
                    &BsB[buf][(row << 7) + (kb ^ ((row & 7) << 4))]);
            }
#pragma unroll
            for (int mi = 0; mi < 2; ++mi)
#pragma unroll
                for (int ni = 0; ni < 2; ++ni)
                    acc[mi][ni] = __builtin_amdgcn_mfma_f32_16x16x32_bf16(
                        af[mi], bfr[ni], acc[mi][ni], 0, 0, 0);
        }
    };

    // prologue
    LOAD(0);
    WRITE(0);
    __syncthreads();
    int cur = 0;
    for (int k0 = 64; k0 < KTOT; k0 += 64) {
        LOAD(k0);            // issue next-tile global loads early (overlap w/ MFMA)
        COMPUTE(cur);
        WRITE(cur ^ 1);      // vmcnt wait lands here, after compute
        __syncthreads();     // one barrier per K-iter
        cur ^= 1;
    }
    COMPUTE(cur);

    // ---- epilogue ----
    const float* be = bias + (size_t)e * NTOT + nchunk * 128 + wc * 32;
#pragma unroll
    for (int mi = 0; mi < 2; ++mi) {
        const int rl0 = wr * 32 + mi * 16 + fq * 4;
#pragma unroll
        for (int ni = 0; ni < 2; ++ni) {
            const int coll = ni * 16 + fr;
            const int colg = nchunk * 128 + wc * 32 + coll;
            const float bb = be[coll];
#pragma unroll
            for (int r2 = 0; r2 < 4; ++r2) {
                const int rl = rl0 + r2;
                if (rl < ns) {
                    float v = acc[mi][ni][r2] + bb;
                    if (RELU) v = fmaxf(v, 0.f);
                    size_t o = (size_t)sidx[rl] * NTOT + colg;
                    if (OUTBF) ((unsigned short*)Cout)[o] = f2bf(v);
                    else       ((float*)Cout)[o] = v;
                }
            }
        }
    }
}

// ---------------- final norm: out = l2norm(l2norm(y2) + x) ----------------
// YB: y2 is bf16 in ws; else y2 is fp32 in-place in out.
template<bool YB>
__global__ void norm_kernel(const float* __restrict__ emb,
                            const unsigned short* __restrict__ y2b,
                            float* __restrict__ out) {
    const int row  = blockIdx.x * 4 + (threadIdx.x >> 6);
    const int lane = threadIdx.x & 63;
    const float* x = emb + (size_t)row * H_DIM;
    float* o = out + (size_t)row * H_DIM;

    float s1 = 0.f, s2 = 0.f, s3 = 0.f;
    if (YB) {
        const uint32_t* yrow = reinterpret_cast<const uint32_t*>(y2b + (size_t)row * H_DIM);
        float y0v[6], y1v[6];
        float2 xv[6];
#pragma unroll
        for (int c = 0; c < 6; ++c) {
            uint32_t u = yrow[c * 64 + lane];
            float y0 = __uint_as_float(u << 16);
            float y1 = __uint_as_float(u & 0xffff0000u);
            float2 xx = *reinterpret_cast<const float2*>(x + 2 * (c * 64 + lane));
            y0v[c] = y0; y1v[c] = y1; xv[c] = xx;
            s1 = fmaf(y0, y0, s1); s1 = fmaf(y1, y1, s1);
            s2 = fmaf(y0, xx.x, s2); s2 = fmaf(y1, xx.y, s2);
            s3 = fmaf(xx.x, xx.x, s3); s3 = fmaf(xx.y, xx.y, s3);
        }
#pragma unroll
        for (int m = 1; m < 64; m <<= 1) {
            s1 += __shfl_xor(s1, m); s2 += __shfl_xor(s2, m); s3 += __shfl_xor(s3, m);
        }
        const float n1 = fmaxf(sqrtf(s1), 1e-6f);
        const float i1 = 1.f / n1;
        const float t  = s1 * i1 * i1 + 2.f * s2 * i1 + s3;
        const float i2 = 1.f / fmaxf(sqrtf(t), 1e-12f);
#pragma unroll
        for (int c = 0; c < 6; ++c) {
            float2 ov;
            ov.x = (y0v[c] * i1 + xv[c].x) * i2;
            ov.y = (y1v[c] * i1 + xv[c].y) * i2;
            *reinterpret_cast<float2*>(o + 2 * (c * 64 + lane)) = ov;
        }
    } else {
        f32x4 yv[3], xv[3];
#pragma unroll
        for (int c = 0; c < 3; ++c) {
            int col = c * 256 + lane * 4;
            yv[c] = *reinterpret_cast<const f32x4*>(o + col);
            xv[c] = *reinterpret_cast<const f32x4*>(x + col);
#pragma unroll
            for (int i = 0; i < 4; ++i) {
                s1 = fmaf(yv[c][i], yv[c][i], s1);
                s2 = fmaf(yv[c][i], xv[c][i], s2);
                s3 = fmaf(xv[c][i], xv[c][i], s3);
            }
        }
#pragma unroll
        for (int m = 1; m < 64; m <<= 1) {
            s1 += __shfl_xor(s1, m); s2 += __shfl_xor(s2, m); s3 += __shfl_xor(s3, m);
        }
        const float n1 = fmaxf(sqrtf(s1), 1e-6f);
        const float i1 = 1.f / n1;
        const float t  = s1 * i1 * i1 + 2.f * s2 * i1 + s3;
        const float i2 = 1.f / fmaxf(sqrtf(t), 1e-12f);
#pragma unroll
        for (int c = 0; c < 3; ++c) {
            int col = c * 256 + lane * 4;
            f32x4 ov;
#pragma unroll
            for (int i = 0; i < 4; ++i) ov[i] = (yv[c][i] * i1 + xv[c][i]) * i2;
            *reinterpret_cast<f32x4*>(o + col) = ov;
        }
    }
}

// ---------------- fallback (fp32 fused) if ws too small ----------------
#define TILE 64
#define NTHR 256
#define BK   64
__global__ __launch_bounds__(NTHR, 2)
void moe_fused_fallback(const float* __restrict__ emb,
                        const float* __restrict__ W1,
                        const float* __restrict__ b1,
                        const float* __restrict__ W2,
                        const float* __restrict__ b2,
                        const int* __restrict__ counts,
                        const int* __restrict__ buckets,
                        float* __restrict__ out) {
    __shared__ float Xs[TILE][BK];
    __shared__ __hip_bfloat16 Hs[TILE][HH];
    __shared__ int   sidx[TILE];
    __shared__ float s_in1[TILE];
    __shared__ float s_in2[TILE];

    const int e    = blockIdx.y;
    const int cnt  = counts[e * CSTRIDE];
    const int base = blockIdx.x * TILE;
    if (base >= cnt) return;
    const int ns = min(TILE, cnt - base);
    const int tid = threadIdx.x;
    const int sg  = tid >> 5;
    const int cg  = tid & 31;

    if (tid < TILE) sidx[tid] = buckets[e * B_N + base + ((tid < ns) ? tid : 0)];
    __syncthreads();

    float acc[8][12];
#pragma unroll
    for (int i = 0; i < 8; ++i)
#pragma unroll
        for (int j = 0; j < 12; ++j) acc[i][j] = 0.f;

    const float* W1e = W1 + (size_t)e * H_DIM * HH;
    const int r = tid >> 2, q = tid & 3;
    const float* xrow = emb + (size_t)sidx[r] * H_DIM;

    for (int kk = 0; kk < H_DIM; kk += BK) {
#pragma unroll
        for (int i = 0; i < 4; ++i)
            *reinterpret_cast<float4*>(&Xs[r][q * 16 + i * 4]) =
                *reinterpret_cast<const float4*>(xrow + kk + q * 16 + i * 4);
        __syncthreads();
#pragma unroll 2
        for (int k = 0; k < BK; ++k) {
            float xv[8], wv[12];
            const float* wrow = W1e + (size_t)(kk + k) * HH + cg;
#pragma unroll
            for (int j = 0; j < 12; ++j) wv[j] = wrow[j * 32];
#pragma unroll
            for (int i = 0; i < 8; ++i) xv[i] = Xs[sg * 8 + i][k];
#pragma unroll
            for (int i = 0; i < 8; ++i)
#pragma unroll
                for (int j = 0; j < 12; ++j) acc[i][j] = fmaf(xv[i], wv[j], acc[i][j]);
        }
        __syncthreads();
    }
    const float* b1e = b1 + e * HH;
#pragma unroll
    for (int j = 0; j < 12; ++j) {
        float bb = b1e[cg + j * 32];
#pragma unroll
        for (int i = 0; i < 8; ++i)
            Hs[sg * 8 + i][cg + j * 32] = __float2bfloat16(fmaxf(acc[i][j] + bb, 0.f));
    }
    __syncthreads();

    const float* W2e = W2 + (size_t)e * HH * H_DIM;
    const float* b2e = b2 + e * H_DIM;
    float S1[8], S2[8], S3[8];
#pragma unroll
    for (int i = 0; i < 8; ++i) { S1[i] = 0.f; S2[i] = 0.f; S3[i] = 0.f; }

    for (int hb = 0; hb < H_DIM; hb += 384) {
        float acc2[8][12];
#pragma unroll
        for (int i = 0; i < 8; ++i)
#pragma unroll
            for (int j = 0; j < 12; ++j) acc2[i][j] = 0.f;
#pragma unroll 2
        for (int k = 0; k < HH; ++k) {
            float hv[8], wv[12];
            const float* wrow = W2e + (size_t)k * H_DIM + hb + cg;
#pragma unroll
            for (int j = 0; j < 12; ++j) wv[j] = wrow[j * 32];
#pragma unroll
            for (int i = 0; i < 8; ++i) hv[i] = __bfloat162float(Hs[sg * 8 + i][k]);
#pragma unroll
            for (int i = 0; i < 8; ++i)
#pragma unroll
                for (int j = 0; j < 12; ++j) acc2[i][j] = fmaf(hv[i], wv[j], acc2[i][j]);
        }
#pragma unroll
        for (int j = 0; j < 12; ++j) {
            int col = hb + cg + j * 32;
            float bb = b2e[col];
#pragma unroll
            for (int i = 0; i < 8; ++i) {
                int s = sg * 8 + i;
                float y = acc2[i][j] + bb;
                size_t o = (size_t)sidx[s] * H_DIM + col;
                float x = emb[o];
                S1[i] = fmaf(y, y, S1[i]);
                S2[i] = fmaf(y, x, S2[i]);
                S3[i] = fmaf(x, x, S3[i]);
                if (s < ns) out[o] = y;
            }
        }
    }
#pragma unroll
    for (int i = 0; i < 8; ++i) {
        float v1 = S1[i], v2 = S2[i], v3 = S3[i];
#pragma unroll
        for (int m = 1; m < 32; m <<= 1) {
            v1 += __shfl_xor(v1, m); v2 += __shfl_xor(v2, m); v3 += __shfl_xor(v3, m);
        }
        if (cg == 0) {
            float n1 = fmaxf(sqrtf(v1), 1e-6f);
            float t  = v1 / (n1 * n1) + 2.f * v2 / n1 + v3;
            s_in1[sg * 8 + i] = 1.f / n1;
            s_in2[sg * 8 + i] = 1.f / fmaxf(sqrtf(t), 1e-12f);
        }
    }
    __syncthreads();
#pragma unroll
    for (int i = 0; i < 8; ++i) {
        int s = sg * 8 + i;
        if (s >= ns) continue;
        float in1 = s_in1[s], in2 = s_in2[s];
        size_t rowo = (size_t)sidx[s] * H_DIM;
#pragma unroll
        for (int j = 0; j < 24; ++j) {
            int col = cg + j * 32;
            out[rowo + col] = (out[rowo + col] * in1 + emb[rowo + col]) * in2;
        }
    }
}

// ---------------- launch ----------------
extern "C" void kernel_launch(void* const* d_in, const int* in_sizes, int n_in,
                              void* d_out, int out_size, void* d_ws, size_t ws_size,
                              hipStream_t stream) {
    const float* emb    = (const float*)d_in[0];
    const float* logits = (const float*)d_in[1];
    const float* W1     = (const float*)d_in[2];
    const float* b1     = (const float*)d_in[3];
    const float* W2     = (const float*)d_in[4];
    const float* b2     = (const float*)d_in[5];
    float* out = (float*)d_out;

    int* counts  = (int*)d_ws;                              // 8 counters, 128B apart (1KB)
    int* buckets = (int*)((char*)d_ws + 1024);              // [8][16384] int (512KB)
    unsigned short* W1T  = (unsigned short*)((char*)d_ws + 1024 + 524288);
    unsigned short* W2T  = W1T + (size_t)NE * HH * H_DIM;   // each 4.72MB
    unsigned short* Hws  = W2T + (size_t)NE * HH * H_DIM;   // 12.6MB
    unsigned short* y2ws = Hws + (size_t)B_N * HH;          // 25.2MB
    const size_t need_base = 1024 + 524288
                           + 2 * (size_t)NE * HH * H_DIM * sizeof(unsigned short)
                           + (size_t)B_N * HH * sizeof(unsigned short);
    const size_t need_bf16 = need_base + (size_t)B_N * H_DIM * sizeof(unsigned short);

    if (ws_size >= need_base) {
        transpose_cvt_kernel<<<dim3(288, NE, 2), 256, 0, stream>>>(W1, W2, W1T, W2T, counts);
        route_kernel<<<B_N / 256, 256, 0, stream>>>(logits, counts, buckets);
        gemm_kernel<H_DIM, HH, true, true, true>
            <<<NE * 256 * 3, 512, 0, stream>>>(emb, W1T, b1, counts, buckets, Hws);
        if (ws_size >= need_bf16) {
            gemm_kernel<HH, H_DIM, false, false, true>
                <<<NE * 256 * 6, 512, 0, stream>>>(Hws, W2T, b2, counts, buckets, y2ws);
            norm_kernel<true><<<B_N / 4, 256, 0, stream>>>(emb, y2ws, out);
        } else {
            gemm_kernel<HH, H_DIM, false, false, false>
                <<<NE * 256 * 6, 512, 0, stream>>>(Hws, W2T, b2, counts, buckets, out);
            norm_kernel<false><<<B_N / 4, 256, 0, stream>>>(emb, nullptr, out);
        }
    } else {
        zero_counts_kernel<<<1, 64, 0, stream>>>(counts);
        route_kernel<<<B_N / 256, 256, 0, stream>>>(logits, counts, buckets);
        moe_fused_fallback<<<dim3(B_N / TILE, NE), NTHR, 0, stream>>>(
            emb, W1, b1, W2, b2, counts, buckets, out);
    }
}